// Round 1
// baseline (237.816 us; speedup 1.0000x reference)
//
#include <hip/hip_runtime.h>
#include <stdint.h>

typedef __attribute__((ext_vector_type(4))) float f32x4;
typedef __attribute__((ext_vector_type(8))) short s16x8;

static constexpr int S_TOK = 4096;   // B*T
static constexpr int CDIM  = 1024;
static constexpr int HDIM  = 1024;
static constexpr int H2    = 2048;
static constexpr int NEXP  = 8;

#define BM 128
#define BN 128
#define BK 32
#define NTHR 512

__device__ __forceinline__ unsigned short f2bf(float f) {
  union { float f; uint32_t u; } c; c.f = f;
  uint32_t u = c.u;
  u += 0x7fffu + ((u >> 16) & 1u);   // RNE
  return (unsigned short)(u >> 16);
}

__device__ __forceinline__ void gload16(const void* g, void* l) {
  __builtin_amdgcn_global_load_lds(
      (const __attribute__((address_space(1))) void*)g,
      (__attribute__((address_space(3))) void*)l, 16, 0, 0);
}

// ---------- elementwise cast fp32 -> bf16 (x4 vectorized) ----------
__global__ void cast_bf16_kernel(const float* __restrict__ src,
                                 unsigned short* __restrict__ dst, int n4) {
  int i = blockIdx.x * blockDim.x + threadIdx.x;
  const int st = gridDim.x * blockDim.x;
  for (; i < n4; i += st) {
    float4 v = reinterpret_cast<const float4*>(src)[i];
    ushort4 o;
    o.x = f2bf(v.x); o.y = f2bf(v.y); o.z = f2bf(v.z); o.w = f2bf(v.w);
    reinterpret_cast<ushort4*>(dst)[i] = o;
  }
}

// ---------- transpose + cast: src fp32 [R, Cc] -> dst bf16 [Cc, R] ----------
__global__ void transpose_cast_kernel(const float* __restrict__ src,
                                      unsigned short* __restrict__ dst,
                                      int R, int Cc) {
  __shared__ float t[32][33];
  const size_t zoff = (size_t)blockIdx.z * R * Cc;
  src += zoff; dst += zoff;
  const int r0 = blockIdx.y * 32;
  const int c0 = blockIdx.x * 32;
  const int tid = threadIdx.x;
#pragma unroll
  for (int i = 0; i < 4; ++i) {
    int idx = tid + i * 256;
    int r = idx >> 5, c = idx & 31;
    t[r][c] = src[(size_t)(r0 + r) * Cc + c0 + c];
  }
  __syncthreads();
#pragma unroll
  for (int i = 0; i < 4; ++i) {
    int idx = tid + i * 256;
    int r = idx >> 5, c = idx & 31;
    dst[(size_t)(c0 + r) * R + r0 + c] = f2bf(t[c][r]);
  }
}

// ---------- router: fp32 logits, softmax, top-2 -> dense weight matrix ----------
__global__ void router_kernel(const float* __restrict__ x, const float* __restrict__ wg,
                              const float* __restrict__ gb, float* __restrict__ wdense) {
  const int l = threadIdx.x & 63;
  const int wid = threadIdx.x >> 6;
  const int s = blockIdx.x * 4 + wid;
  const float* xr = x + (size_t)s * CDIM;
  float acc[NEXP];
#pragma unroll
  for (int e = 0; e < NEXP; ++e) acc[e] = 0.f;
  for (int c = l; c < CDIM; c += 64) {
    float xv = xr[c];
    const float* wr_ = wg + (size_t)c * NEXP;
#pragma unroll
    for (int e = 0; e < NEXP; ++e) acc[e] += xv * wr_[e];
  }
#pragma unroll
  for (int e = 0; e < NEXP; ++e) {
#pragma unroll
    for (int off = 32; off > 0; off >>= 1) acc[e] += __shfl_xor(acc[e], off);
    acc[e] += gb[e];
  }
  float m = acc[0];
#pragma unroll
  for (int e = 1; e < NEXP; ++e) m = fmaxf(m, acc[e]);
  float ex[NEXP], sum = 0.f;
#pragma unroll
  for (int e = 0; e < NEXP; ++e) { ex[e] = __expf(acc[e] - m); sum += ex[e]; }
  int i0 = 0;
#pragma unroll
  for (int e = 1; e < NEXP; ++e) if (acc[e] > acc[i0]) i0 = e;  // strict > : lowest idx on tie
  int i1 = (i0 == 0) ? 1 : 0;
#pragma unroll
  for (int e = 0; e < NEXP; ++e) {
    if (e == i0) continue;
    if (acc[e] > acc[i1]) i1 = e;
  }
  if (l == 0) {
    const float inv = 1.f / sum;
#pragma unroll
    for (int e = 0; e < NEXP; ++e) wdense[(size_t)s * NEXP + e] = 0.f;
    wdense[(size_t)s * NEXP + i0] = ex[i0] * inv;
    wdense[(size_t)s * NEXP + i1] = ex[i1] * inv;
  }
}

// ---------- shared GEMM pieces (m97-style: gload_lds, linear LDS, 2 barriers) ----------
// A: [M,K] bf16 row-major.  Bt: [N,K] bf16 row-major (i.e. B^T).  D = A*B.
__device__ __forceinline__ void stage_tile(const unsigned short* ga, int lda,
                                           const unsigned short* gb, int ldb,
                                           unsigned short* As, unsigned short* Bs, int tid) {
  const int row = tid >> 2;
  const int c = (tid & 3) << 3;
  gload16(ga + (size_t)row * lda + c, As + tid * 8);
  gload16(gb + (size_t)row * ldb + c, Bs + tid * 8);
}

__device__ __forceinline__ void ktile_mfma(const unsigned short* As, const unsigned short* Bs,
                                           int lr, int lk, int wr, int wc, f32x4 acc[2][4]) {
  s16x8 a[2], b[4];
#pragma unroll
  for (int fm = 0; fm < 2; ++fm)
    a[fm] = *reinterpret_cast<const s16x8*>(As + (wr * 32 + fm * 16 + lr) * BK + lk);
#pragma unroll
  for (int fn = 0; fn < 4; ++fn)
    b[fn] = *reinterpret_cast<const s16x8*>(Bs + (wc * 64 + fn * 16 + lr) * BK + lk);
#pragma unroll
  for (int fm = 0; fm < 2; ++fm)
#pragma unroll
    for (int fn = 0; fn < 4; ++fn)
      acc[fm][fn] = __builtin_amdgcn_mfma_f32_16x16x32_bf16(a[fm], b[fn], acc[fm][fn], 0, 0, 0);
}

// D[M,N] = A * Bt^T, fp32 store
__global__ __launch_bounds__(NTHR) void gemm_bt_store_kernel(
    const unsigned short* __restrict__ A, const unsigned short* __restrict__ Bt,
    float* __restrict__ D, int N, int K) {
  __shared__ unsigned short As[BM * BK];
  __shared__ unsigned short Bs[BN * BK];
  const int tid = threadIdx.x;
  const int l = tid & 63, wid = tid >> 6;
  const int wr = wid >> 1, wc = wid & 1;     // 4x2 wave grid; wave tile 32x64
  const int lr = l & 15, lk = (l >> 4) << 3;
  const int m0 = blockIdx.x * BM, n0 = blockIdx.y * BN;
  f32x4 acc[2][4] = {};
  const unsigned short* pa = A + (size_t)m0 * K;
  const unsigned short* pb = Bt + (size_t)n0 * K;
  for (int k0 = 0; k0 < K; k0 += BK) {
    stage_tile(pa + k0, K, pb + k0, K, As, Bs, tid);
    __syncthreads();
    ktile_mfma(As, Bs, lr, lk, wr, wc, acc);
    __syncthreads();
  }
  const int rb = m0 + wr * 32 + ((l >> 4) << 2);
  const int cb = n0 + wc * 64 + lr;
#pragma unroll
  for (int fm = 0; fm < 2; ++fm)
#pragma unroll
    for (int fn = 0; fn < 4; ++fn)
#pragma unroll
      for (int r = 0; r < 4; ++r)
        D[(size_t)(rb + fm * 16 + r) * N + cb + fn * 16] = acc[fm][fn][r];
}

// ---------- swiglu: T fp32 [S, 2H] -> Hout bf16 [S, H] ----------
__global__ void swiglu_kernel(const float* __restrict__ T, unsigned short* __restrict__ Hout) {
  int i = blockIdx.x * blockDim.x + threadIdx.x;
  const int n4 = S_TOK * HDIM / 4;
  const int st = gridDim.x * blockDim.x;
  for (; i < n4; i += st) {
    const int s = i >> 8;      // HDIM/4 = 256
    const int j4 = i & 255;
    const float4 a = *reinterpret_cast<const float4*>(T + (size_t)s * H2 + j4 * 4);
    const float4 b = *reinterpret_cast<const float4*>(T + (size_t)s * H2 + HDIM + j4 * 4);
    float4 h;
    h.x = (a.x / (1.f + __expf(-a.x))) * b.x;
    h.y = (a.y / (1.f + __expf(-a.y))) * b.y;
    h.z = (a.z / (1.f + __expf(-a.z))) * b.z;
    h.w = (a.w / (1.f + __expf(-a.w))) * b.w;
    ushort4 o;
    o.x = f2bf(h.x); o.y = f2bf(h.y); o.z = f2bf(h.z); o.w = f2bf(h.w);
    reinterpret_cast<ushort4*>(Hout)[i] = o;
  }
}

// ---------- combine: out = Hs@wso + sum_e wdense[:,e] * (Hr@w2[e]) ----------
// grid.z splits the 9 passes 3-ways: z0 -> d_out, z1 -> part1, z2 -> part2
__global__ __launch_bounds__(NTHR) void combine_kernel(
    const unsigned short* __restrict__ Hs, const unsigned short* __restrict__ Hr,
    const unsigned short* __restrict__ wso_t, const unsigned short* __restrict__ w2t,
    const float* __restrict__ wdense,
    float* __restrict__ out0, float* __restrict__ out1, float* __restrict__ out2) {
  __shared__ unsigned short As[BM * BK];
  __shared__ unsigned short Bs[BN * BK];
  const int tid = threadIdx.x;
  const int l = tid & 63, wid = tid >> 6;
  const int wr = wid >> 1, wc = wid & 1;
  const int lr = l & 15, lk = (l >> 4) << 3;
  const int m0 = blockIdx.x * BM, n0 = blockIdx.y * BN;
  const int z = blockIdx.z;
  float* outp = (z == 0) ? out0 : ((z == 1) ? out1 : out2);
  const int rb = m0 + wr * 32 + ((l >> 4) << 2);
  const int cb = n0 + wc * 64 + lr;
  f32x4 master[2][4] = {};
  const int pbeg = z * 3;
  for (int p = pbeg; p < pbeg + 3; ++p) {
    const unsigned short* Ab = (p == 0) ? Hs : Hr;
    const unsigned short* Bb = (p == 0) ? wso_t
                                        : (w2t + (size_t)(p - 1) * CDIM * HDIM);
    f32x4 acc[2][4] = {};
    const unsigned short* pa = Ab + (size_t)m0 * HDIM;
    const unsigned short* pb = Bb + (size_t)n0 * HDIM;
    for (int k0 = 0; k0 < HDIM; k0 += BK) {
      stage_tile(pa + k0, HDIM, pb + k0, HDIM, As, Bs, tid);
      __syncthreads();
      ktile_mfma(As, Bs, lr, lk, wr, wc, acc);
      __syncthreads();
    }
    if (p == 0) {
#pragma unroll
      for (int fm = 0; fm < 2; ++fm)
#pragma unroll
        for (int fn = 0; fn < 4; ++fn)
          master[fm][fn] += acc[fm][fn];
    } else {
      const int e = p - 1;
#pragma unroll
      for (int fm = 0; fm < 2; ++fm)
#pragma unroll
        for (int r = 0; r < 4; ++r) {
          const float wv = wdense[(size_t)(rb + fm * 16 + r) * NEXP + e];
#pragma unroll
          for (int fn = 0; fn < 4; ++fn)
            master[fm][fn][r] += wv * acc[fm][fn][r];
        }
    }
  }
#pragma unroll
  for (int fm = 0; fm < 2; ++fm)
#pragma unroll
    for (int fn = 0; fn < 4; ++fn)
#pragma unroll
      for (int r = 0; r < 4; ++r)
        outp[(size_t)(rb + fm * 16 + r) * CDIM + cb + fn * 16] = master[fm][fn][r];
}

// ---------- final reduce: out += part1 + part2 ----------
__global__ void reduce_kernel(float* __restrict__ out, const float* __restrict__ p1,
                              const float* __restrict__ p2, int n4) {
  int i = blockIdx.x * blockDim.x + threadIdx.x;
  const int st = gridDim.x * blockDim.x;
  for (; i < n4; i += st) {
    float4 o = reinterpret_cast<float4*>(out)[i];
    const float4 a = reinterpret_cast<const float4*>(p1)[i];
    const float4 b = reinterpret_cast<const float4*>(p2)[i];
    o.x += a.x + b.x; o.y += a.y + b.y; o.z += a.z + b.z; o.w += a.w + b.w;
    reinterpret_cast<float4*>(out)[i] = o;
  }
}

extern "C" void kernel_launch(void* const* d_in, const int* in_sizes, int n_in,
                              void* d_out, int out_size, void* d_ws, size_t ws_size,
                              hipStream_t stream) {
  (void)in_sizes; (void)n_in; (void)out_size; (void)ws_size;
  const float* x   = (const float*)d_in[0];
  const float* wsi = (const float*)d_in[1];   // [C, 2H]
  const float* wso = (const float*)d_in[2];   // [H, C]
  const float* w1s = (const float*)d_in[3];   // [C, 2H]
  const float* w2  = (const float*)d_in[4];   // [E, H, C]
  const float* wg  = (const float*)d_in[5];   // [C, E]
  const float* gb  = (const float*)d_in[6];   // [E]
  float* out = (float*)d_out;

  char* w = (char*)d_ws;
  auto alloc = [&](size_t bytes) {
    char* p = w; w += (bytes + 255) & ~(size_t)255; return p;
  };
  unsigned short* xb     = (unsigned short*)alloc((size_t)S_TOK * CDIM * 2);
  unsigned short* wsi_t  = (unsigned short*)alloc((size_t)H2 * CDIM * 2);
  unsigned short* w1s_t  = (unsigned short*)alloc((size_t)H2 * CDIM * 2);
  unsigned short* wso_t  = (unsigned short*)alloc((size_t)CDIM * HDIM * 2);
  unsigned short* w2t    = (unsigned short*)alloc((size_t)NEXP * CDIM * HDIM * 2);
  unsigned short* Hs     = (unsigned short*)alloc((size_t)S_TOK * HDIM * 2);
  unsigned short* Hr     = (unsigned short*)alloc((size_t)S_TOK * HDIM * 2);
  float*  Tbuf   = (float*)alloc((size_t)S_TOK * H2 * 4);
  float*  wdense = (float*)alloc((size_t)S_TOK * NEXP * 4);
  float*  part1  = (float*)alloc((size_t)S_TOK * CDIM * 4);
  float*  part2  = (float*)alloc((size_t)S_TOK * CDIM * 4);

  // 1. casts / transposes to bf16 B^T layouts
  cast_bf16_kernel<<<2048, 256, 0, stream>>>(x, xb, S_TOK * CDIM / 4);
  transpose_cast_kernel<<<dim3(H2 / 32, CDIM / 32, 1), 256, 0, stream>>>(wsi, wsi_t, CDIM, H2);
  transpose_cast_kernel<<<dim3(H2 / 32, CDIM / 32, 1), 256, 0, stream>>>(w1s, w1s_t, CDIM, H2);
  transpose_cast_kernel<<<dim3(CDIM / 32, HDIM / 32, 1), 256, 0, stream>>>(wso, wso_t, HDIM, CDIM);
  transpose_cast_kernel<<<dim3(CDIM / 32, HDIM / 32, NEXP), 256, 0, stream>>>(w2, w2t, HDIM, CDIM);

  // 2. router (fp32)
  router_kernel<<<S_TOK / 4, 256, 0, stream>>>(x, wg, gb, wdense);

  // 3. shared-expert hidden: Hs = swiglu(x @ w_shared_in)
  gemm_bt_store_kernel<<<dim3(S_TOK / BM, H2 / BN), NTHR, 0, stream>>>(xb, wsi_t, Tbuf, H2, CDIM);
  swiglu_kernel<<<2048, 256, 0, stream>>>(Tbuf, Hs);

  // 4. routed hidden: Hr = swiglu(x @ w1_shared)
  gemm_bt_store_kernel<<<dim3(S_TOK / BM, H2 / BN), NTHR, 0, stream>>>(xb, w1s_t, Tbuf, H2, CDIM);
  swiglu_kernel<<<2048, 256, 0, stream>>>(Tbuf, Hr);

  // 5. combine shared-out + 8 weighted expert GEMMs (3-way z-split), then reduce
  combine_kernel<<<dim3(S_TOK / BM, CDIM / BN, 3), NTHR, 0, stream>>>(
      Hs, Hr, wso_t, w2t, wdense, out, part1, part2);
  reduce_kernel<<<2048, 256, 0, stream>>>(out, part1, part2, S_TOK * CDIM / 4);
}